// Round 10
// baseline (189.263 us; speedup 1.0000x reference)
//
#include <hip/hip_runtime.h>
#include <math.h>

#define D_DIM 1280
#define ODIM  510
#define REPS  8      // diagnostic amplification factor (1/REPS applied to acc)

typedef short bf16x8 __attribute__((ext_vector_type(8)));   // 8 bf16 = 4 VGPRs
typedef float f32x4  __attribute__((ext_vector_type(4)));
typedef unsigned uintx4 __attribute__((ext_vector_type(4)));

// pack two fp32 -> packed bf16 pair (round-half-up)
__device__ __forceinline__ unsigned pkbf(float a, float b) {
  unsigned ua = __float_as_uint(a), ub = __float_as_uint(b);
  return ((ua + 0x8000u) >> 16) | ((ub + 0x8000u) & 0xffff0000u);
}

union BFU { uintx4 u; bf16x8 h; };

// DIAGNOSTIC build of the round-9 fused kernel: K-loop executed REPS times with
// pointers offset by rep*z (z==0 at runtime, opaque to the compiler) so every
// load/convert/MFMA re-executes. acc accumulates REPS identical contributions;
// epilogue scales by 1/REPS (exact: 2^-3). Purpose: single dispatch > 44 us so
// the kernel finally lands in rocprof's top-5 with full counters.
__global__ __launch_bounds__(256, 2) void pcmd_diag(
    const float* __restrict__ X,   // [512][1280]
    const float* __restrict__ W,   // [2560][2] (first 1280 rows = Wp)
    const float* __restrict__ b,   // [2]
    float* __restrict__ out,       // [510][510][2]
    int z)                         // runtime 0
{
  __shared__ float sR[4][2][16][17];   // [wave][ch][i][j] partials, padded

  // linear block id -> (bi, bj), bi <= bj
  const int t = (int)blockIdx.x;       // 0..527
  int bi = (int)((65.0 - sqrt(4225.0 - 8.0 * (double)t)) * 0.5);
  {
    int s0 = bi * 32 - (bi * (bi - 1)) / 2;
    if (t < s0) { --bi; }
    int s1 = (bi + 1) * 32 - ((bi + 1) * bi) / 2;
    if (t >= s1) { ++bi; }
  }
  const int start = bi * 32 - (bi * (bi - 1)) / 2;
  const int bj = bi + (t - start);

  const int tid  = threadIdx.x;
  const int lane = tid & 63;
  const int wv   = tid >> 6;           // K-quarter owner
  const int m    = lane & 15;
  const int quad = lane >> 4;

  const int i_base = 1 + bi * 16;
  const int j_base = 1 + bj * 16;
  int gi = i_base + m; if (gi > 511) gi = 511;   // clamp; masked at store
  int gj = j_base + m; if (gj > 511) gj = 511;

  const int k0 = wv * 320;             // this wave's K-quarter
  const float* pxi0 = X + (size_t)gi * D_DIM + k0 + quad * 8;
  const float* pxj0 = X + (size_t)gj * D_DIM + k0 + quad * 8;
  const float* pw0  = W + 2 * (k0 + quad * 8);

  f32x4 acc0 = {0.f, 0.f, 0.f, 0.f};
  f32x4 acc1 = {0.f, 0.f, 0.f, 0.f};

  #pragma unroll 1
  for (int rep = 0; rep < REPS; ++rep) {
    // z==0 at runtime -> same addresses every rep; opaque to the compiler.
    const float* pxi = pxi0 + (size_t)rep * z;
    const float* pxj = pxj0 + (size_t)rep * z;
    const float* pw  = pw0  + (size_t)rep * z;

    // software pipeline over 10 K-steps, prefetch distance 4 (identical to round 9)
    float4 rxi[4][2], rxj[4][2], rw[4][4];
    #pragma unroll
    for (int s = 0; s < 4; ++s) {
      rxi[s][0] = *(const float4*)(pxi + s * 32);
      rxi[s][1] = *(const float4*)(pxi + s * 32 + 4);
      rxj[s][0] = *(const float4*)(pxj + s * 32);
      rxj[s][1] = *(const float4*)(pxj + s * 32 + 4);
      rw[s][0]  = *(const float4*)(pw + s * 64);
      rw[s][1]  = *(const float4*)(pw + s * 64 + 4);
      rw[s][2]  = *(const float4*)(pw + s * 64 + 8);
      rw[s][3]  = *(const float4*)(pw + s * 64 + 12);
    }

    #pragma unroll
    for (int s = 0; s < 10; ++s) {
      const int cur = s & 3;
      float4 xi0 = rxi[cur][0], xi1 = rxi[cur][1];
      float4 xj0 = rxj[cur][0], xj1 = rxj[cur][1];
      float4 w0 = rw[cur][0], w1 = rw[cur][1], w2 = rw[cur][2], w3 = rw[cur][3];
      if (s + 4 < 10) {
        rxi[cur][0] = *(const float4*)(pxi + (s + 4) * 32);
        rxi[cur][1] = *(const float4*)(pxi + (s + 4) * 32 + 4);
        rxj[cur][0] = *(const float4*)(pxj + (s + 4) * 32);
        rxj[cur][1] = *(const float4*)(pxj + (s + 4) * 32 + 4);
        rw[cur][0]  = *(const float4*)(pw + (s + 4) * 64);
        rw[cur][1]  = *(const float4*)(pw + (s + 4) * 64 + 4);
        rw[cur][2]  = *(const float4*)(pw + (s + 4) * 64 + 8);
        rw[cur][3]  = *(const float4*)(pw + (s + 4) * 64 + 12);
      }

      BFU a0, a1, bb;
      a0.u.x = pkbf(xi0.x * w0.x, xi0.y * w0.z);
      a0.u.y = pkbf(xi0.z * w1.x, xi0.w * w1.z);
      a0.u.z = pkbf(xi1.x * w2.x, xi1.y * w2.z);
      a0.u.w = pkbf(xi1.z * w3.x, xi1.w * w3.z);
      a1.u.x = pkbf(xi0.x * w0.y, xi0.y * w0.w);
      a1.u.y = pkbf(xi0.z * w1.y, xi0.w * w1.w);
      a1.u.z = pkbf(xi1.x * w2.y, xi1.y * w2.w);
      a1.u.w = pkbf(xi1.z * w3.y, xi1.w * w3.w);
      bb.u.x = pkbf(xj0.x, xj0.y);
      bb.u.y = pkbf(xj0.z, xj0.w);
      bb.u.z = pkbf(xj1.x, xj1.y);
      bb.u.w = pkbf(xj1.z, xj1.w);

      acc0 = __builtin_amdgcn_mfma_f32_16x16x32_bf16(a0.h, bb.h, acc0, 0, 0, 0);
      acc1 = __builtin_amdgcn_mfma_f32_16x16x32_bf16(a1.h, bb.h, acc1, 0, 0, 0);
    }
  }

  // undo amplification (exact power-of-2 scale)
  const float inv = 1.0f / (float)REPS;
  #pragma unroll
  for (int r = 0; r < 4; ++r) { acc0[r] *= inv; acc1[r] *= inv; }

  // C/D layout: col = lane&15 (j), row = quad*4 + reg (i)
  #pragma unroll
  for (int r = 0; r < 4; ++r) {
    sR[wv][0][quad * 4 + r][m] = acc0[r];
    sR[wv][1][quad * 4 + r][m] = acc1[r];
  }
  __syncthreads();

  const float b0 = b[0], b1 = b[1];
  const int il = tid >> 4, jl = tid & 15;

  {
    const int i = i_base + il, j = j_base + jl;
    if (i <= ODIM && j <= ODIM) {
      float2 v;
      v.x = sR[0][0][il][jl] + sR[1][0][il][jl] + sR[2][0][il][jl] + sR[3][0][il][jl] + b0;
      v.y = sR[0][1][il][jl] + sR[1][1][il][jl] + sR[2][1][il][jl] + sR[3][1][il][jl] + b1;
      *(float2*)(out + ((size_t)(i - 1) * ODIM + (j - 1)) * 2) = v;
    }
  }
  if (bi != bj) {
    const int i = j_base + il, j = i_base + jl;
    if (i <= ODIM && j <= ODIM) {
      float2 v;
      v.x = sR[0][0][jl][il] + sR[1][0][jl][il] + sR[2][0][jl][il] + sR[3][0][jl][il] + b0;
      v.y = sR[0][1][jl][il] + sR[1][1][jl][il] + sR[2][1][jl][il] + sR[3][1][jl][il] + b1;
      *(float2*)(out + ((size_t)(i - 1) * ODIM + (j - 1)) * 2) = v;
    }
  }
}

extern "C" void kernel_launch(void* const* d_in, const int* in_sizes, int n_in,
                              void* d_out, int out_size, void* d_ws, size_t ws_size,
                              hipStream_t stream) {
  const float* X = (const float*)d_in[0];
  const float* W = (const float*)d_in[1];
  const float* b = (const float*)d_in[2];
  float* out = (float*)d_out;
  (void)in_sizes; (void)n_in; (void)out_size; (void)d_ws; (void)ws_size;

  // z = 0 at runtime; kernel arg is fixed at graph capture (deterministic).
  hipLaunchKernelGGL(pcmd_diag, dim3(528), dim3(256), 0, stream, X, W, b, out, 0);
}

// Round 11
// 70.503 us; speedup vs baseline: 2.6845x; 2.6845x over previous
//
#include <hip/hip_runtime.h>
#include <math.h>

#define D_DIM 1280
#define ODIM  510
#define KSTEPS 40           // 1280 / 32

typedef short bf16x8 __attribute__((ext_vector_type(8)));   // 8 bf16 = 4 VGPRs
typedef float f32x4  __attribute__((ext_vector_type(4)));

// pack two fp32 -> packed bf16 pair (round-half-up)
__device__ __forceinline__ unsigned pkbf(float a, float b) {
  unsigned ua = __float_as_uint(a), ub = __float_as_uint(b);
  return ((ua + 0x8000u) >> 16) | ((ub + 0x8000u) & 0xffff0000u);
}

// Prep: build bf16 planes PRE-SWIZZLED INTO MFMA FRAGMENT ORDER, with +1 row shift.
//   plane row r holds X row r+1 (r=0..510; r=511 zero) so 16-row tile blocks align
//   with output rows (out row = plane row).
//   Granule g = ((R*40 + K)*64 + quad*16 + m), 16 B each:
//     content = plane[R*16+m][K*32 + quad*8 .. +8]
//   => GEMM lane `lane` loads granule base+lane: perfectly coalesced.
__global__ __launch_bounds__(256, 1) void pcmd_prep(
    const float* __restrict__ X,        // [512][1280]
    const float* __restrict__ W,        // [2560][2] (first 1280 rows = Wp)
    unsigned short* __restrict__ Xbf,   // fragment-ordered planes
    unsigned short* __restrict__ A0,
    unsigned short* __restrict__ A1)
{
  int T = (int)blockIdx.x * 256 + (int)threadIdx.x;   // 0..81919
  int r = T / 160;                      // plane row 0..511
  int c = T - r * 160;                  // 8-d granule 0..159
  const int K = c >> 2, quad = c & 3, m = r & 15, R = r >> 4;
  const size_t g = ((size_t)(R * KSTEPS + K) * 64 + quad * 16 + m) * 8;  // ushort offset

  uint4 vx = {0,0,0,0}, v0 = {0,0,0,0}, v1 = {0,0,0,0};
  if (r <= 510) {                       // plane row r <- X row r+1; r=511 stays zero
    const float* px = X + (size_t)(r + 1) * D_DIM + c * 8;
    float4 x0 = *(const float4*)px;
    float4 x1 = *(const float4*)(px + 4);
    const float* pw = W + (size_t)c * 16;   // (w0,w1) pairs for d = c*8 ..
    float4 w0 = *(const float4*)(pw +  0);
    float4 w1 = *(const float4*)(pw +  4);
    float4 w2 = *(const float4*)(pw +  8);
    float4 w3 = *(const float4*)(pw + 12);
    vx.x = pkbf(x0.x, x0.y);            vx.y = pkbf(x0.z, x0.w);
    vx.z = pkbf(x1.x, x1.y);            vx.w = pkbf(x1.z, x1.w);
    v0.x = pkbf(x0.x*w0.x, x0.y*w0.z);  v0.y = pkbf(x0.z*w1.x, x0.w*w1.z);
    v0.z = pkbf(x1.x*w2.x, x1.y*w2.z);  v0.w = pkbf(x1.z*w3.x, x1.w*w3.z);
    v1.x = pkbf(x0.x*w0.y, x0.y*w0.w);  v1.y = pkbf(x0.z*w1.y, x0.w*w1.w);
    v1.z = pkbf(x1.x*w2.y, x1.y*w2.w);  v1.w = pkbf(x1.z*w3.y, x1.w*w3.w);
  }
  *(uint4*)(Xbf + g) = vx;
  *(uint4*)(A0  + g) = v0;
  *(uint4*)(A1  + g) = v1;
}

// GEMM over the upper triangle of the 32x32 tile grid (528 blocks, 16x16 tiles).
// 4 waves split K into quarters (10 fragment-steps each); fragment loads are
// lane-linear (coalesced 1 KB/inst) from the swizzled planes; LDS reduce; the
// off-diagonal blocks also store the transposed tile (output symmetric in i,j).
__global__ __launch_bounds__(256, 2) void pcmd_gemm(
    const unsigned short* __restrict__ Xbf,
    const unsigned short* __restrict__ A0,
    const unsigned short* __restrict__ A1,
    const float* __restrict__ b,
    float* __restrict__ out)            // [510][510][2]
{
  __shared__ float sR[4][2][16][17];    // [wave][ch][i][j] partials, padded

  // linear block id -> (bi, bj), bi <= bj
  const int t = (int)blockIdx.x;        // 0..527
  int bi = (int)((65.0 - sqrt(4225.0 - 8.0 * (double)t)) * 0.5);
  {
    int s0 = bi * 32 - (bi * (bi - 1)) / 2;
    if (t < s0) { --bi; }
    int s1 = (bi + 1) * 32 - ((bi + 1) * bi) / 2;
    if (t >= s1) { ++bi; }
  }
  const int start = bi * 32 - (bi * (bi - 1)) / 2;
  const int bj = bi + (t - start);

  const int tid  = threadIdx.x;
  const int lane = tid & 63;
  const int wv   = tid >> 6;            // K-quarter owner (10 steps each)

  // lane-linear fragment pointers (granule = 8 ushorts = 16 B; step stride = 64 granules)
  const unsigned short* pa0 = A0  + ((size_t)(bi * KSTEPS + wv * 10) * 64 + lane) * 8;
  const unsigned short* pa1 = A1  + ((size_t)(bi * KSTEPS + wv * 10) * 64 + lane) * 8;
  const unsigned short* pb  = Xbf + ((size_t)(bj * KSTEPS + wv * 10) * 64 + lane) * 8;

  // software pipeline over 10 steps, prefetch distance 4
  bf16x8 ra0[4], ra1[4], rb[4];
  #pragma unroll
  for (int s = 0; s < 4; ++s) {
    ra0[s] = *(const bf16x8*)(pa0 + s * 512);
    ra1[s] = *(const bf16x8*)(pa1 + s * 512);
    rb[s]  = *(const bf16x8*)(pb  + s * 512);
  }

  f32x4 acc0 = {0.f, 0.f, 0.f, 0.f};
  f32x4 acc1 = {0.f, 0.f, 0.f, 0.f};

  #pragma unroll
  for (int s = 0; s < 10; ++s) {
    const int cur = s & 3;
    bf16x8 a0 = ra0[cur], a1 = ra1[cur], bb = rb[cur];
    if (s + 4 < 10) {
      ra0[cur] = *(const bf16x8*)(pa0 + (s + 4) * 512);
      ra1[cur] = *(const bf16x8*)(pa1 + (s + 4) * 512);
      rb[cur]  = *(const bf16x8*)(pb  + (s + 4) * 512);
    }
    acc0 = __builtin_amdgcn_mfma_f32_16x16x32_bf16(a0, bb, acc0, 0, 0, 0);
    acc1 = __builtin_amdgcn_mfma_f32_16x16x32_bf16(a1, bb, acc1, 0, 0, 0);
  }

  // C/D layout: col = lane&15 (j), row = quad*4 + reg (i)  [verified m89/m91]
  const int m = lane & 15, quad = lane >> 4;
  #pragma unroll
  for (int r = 0; r < 4; ++r) {
    sR[wv][0][quad * 4 + r][m] = acc0[r];
    sR[wv][1][quad * 4 + r][m] = acc1[r];
  }
  __syncthreads();

  const float b0 = b[0], b1 = b[1];
  const int il = tid >> 4, jl = tid & 15;

  // direct tile: out row = bi*16+il, col = bj*16+jl (plane row == out row)
  {
    const int oi = bi * 16 + il, oj = bj * 16 + jl;
    if (oi < ODIM && oj < ODIM) {
      float2 v;
      v.x = sR[0][0][il][jl] + sR[1][0][il][jl] + sR[2][0][il][jl] + sR[3][0][il][jl] + b0;
      v.y = sR[0][1][il][jl] + sR[1][1][il][jl] + sR[2][1][il][jl] + sR[3][1][il][jl] + b1;
      *(float2*)(out + ((size_t)oi * ODIM + oj) * 2) = v;
    }
  }
  // transposed tile (off-diagonal only); LDS stride 17 -> conflict-free
  if (bi != bj) {
    const int oi = bj * 16 + il, oj = bi * 16 + jl;
    if (oi < ODIM && oj < ODIM) {
      float2 v;
      v.x = sR[0][0][jl][il] + sR[1][0][jl][il] + sR[2][0][jl][il] + sR[3][0][jl][il] + b0;
      v.y = sR[0][1][jl][il] + sR[1][1][jl][il] + sR[2][1][jl][il] + sR[3][1][jl][il] + b1;
      *(float2*)(out + ((size_t)oi * ODIM + oj) * 2) = v;
    }
  }
}

extern "C" void kernel_launch(void* const* d_in, const int* in_sizes, int n_in,
                              void* d_out, int out_size, void* d_ws, size_t ws_size,
                              hipStream_t stream) {
  const float* X = (const float*)d_in[0];
  const float* W = (const float*)d_in[1];
  const float* b = (const float*)d_in[2];
  float* out = (float*)d_out;
  (void)in_sizes; (void)n_in; (void)out_size; (void)ws_size;

  const size_t PLANE = (size_t)512 * D_DIM;        // elements per bf16 plane
  unsigned short* Xbf = (unsigned short*)d_ws;     // 1.31 MB each
  unsigned short* A0  = Xbf + PLANE;
  unsigned short* A1  = A0 + PLANE;

  hipLaunchKernelGGL(pcmd_prep, dim3(320), dim3(256), 0, stream, X, W, Xbf, A0, A1);
  hipLaunchKernelGGL(pcmd_gemm, dim3(528), dim3(256), 0, stream, Xbf, A0, A1, b, out);
}

// Round 12
// 70.153 us; speedup vs baseline: 2.6978x; 1.0050x over previous
//
#include <hip/hip_runtime.h>
#include <math.h>

#define D_DIM 1280
#define ODIM  510
#define KSTEPS 40           // 1280 / 32
#define QK    320           // d's per K-quarter

typedef short bf16x8 __attribute__((ext_vector_type(8)));   // 8 bf16 = 4 VGPRs
typedef float f32x4  __attribute__((ext_vector_type(4)));

// pack two fp32 -> packed bf16 pair (round-half-up)
__device__ __forceinline__ unsigned pkbf(float a, float b) {
  unsigned ua = __float_as_uint(a), ub = __float_as_uint(b);
  return ((ua + 0x8000u) >> 16) | ((ub + 0x8000u) & 0xffff0000u);
}

// Prep v2: build bf16 planes in MFMA fragment order (granule (R,K,quad,m) holds
// plane[R*16+m][K*32+quad*8 ..+8], plane row r = X row r+1, rows 510/511 pad) —
// but route the transpose through LDS so BOTH global sides are coalesced:
//   phase 1: coalesced row reads -> pack -> swizzled LDS write (~2.5-way banks)
//   phase 2: lane-linear LDS read -> coalesced 1KB/inst global stores
// 128 blocks = 32 row-blocks x 4 K-quarters.
__global__ __launch_bounds__(256, 1) void pcmd_prep(
    const float* __restrict__ X,        // [512][1280]
    const float* __restrict__ W,        // [2560][2] (first 1280 rows = Wp)
    unsigned short* __restrict__ Xbf,   // fragment-ordered planes
    unsigned short* __restrict__ A0,
    unsigned short* __restrict__ A1)
{
  __shared__ unsigned short sG[3][10][64][8];   // 30 KB

  const int R   = (int)blockIdx.x >> 2;   // row-block 0..31
  const int q   = (int)blockIdx.x & 3;    // K-quarter 0..3
  const int tid = threadIdx.x;

  // ---- phase 1: 640 tasks = 16 rows x 40 granules ----
  for (int task = tid; task < 640; task += 256) {
    const int lr = task / 40;             // local row 0..15
    const int gc = task - lr * 40;        // granule-in-quarter 0..39
    const int s = gc >> 2, quad = gc & 3;
    const int prow = R * 16 + lr;         // plane row
    uint4 vx = {0,0,0,0}, v0 = {0,0,0,0}, v1 = {0,0,0,0};
    if (prow <= 510) {                    // plane row <- X row prow+1; 511 stays zero
      const float* px = X + (size_t)(prow + 1) * D_DIM + q * QK + gc * 8;
      float4 x0 = *(const float4*)px;
      float4 x1 = *(const float4*)(px + 4);
      const float* pw = W + 2 * (q * QK + gc * 8);
      float4 w0 = *(const float4*)(pw +  0);
      float4 w1 = *(const float4*)(pw +  4);
      float4 w2 = *(const float4*)(pw +  8);
      float4 w3 = *(const float4*)(pw + 12);
      vx.x = pkbf(x0.x, x0.y);            vx.y = pkbf(x0.z, x0.w);
      vx.z = pkbf(x1.x, x1.y);            vx.w = pkbf(x1.z, x1.w);
      v0.x = pkbf(x0.x*w0.x, x0.y*w0.z);  v0.y = pkbf(x0.z*w1.x, x0.w*w1.z);
      v0.z = pkbf(x1.x*w2.x, x1.y*w2.z);  v0.w = pkbf(x1.z*w3.x, x1.w*w3.z);
      v1.x = pkbf(x0.x*w0.y, x0.y*w0.w);  v1.y = pkbf(x0.z*w1.y, x0.w*w1.w);
      v1.z = pkbf(x1.x*w2.y, x1.y*w2.w);  v1.w = pkbf(x1.z*w3.y, x1.w*w3.w);
    }
    const int swzl = quad * 16 + ((lr + quad + 4 * s) & 15);   // bank-spread rotation
    *(uint4*)&sG[0][s][swzl][0] = vx;
    *(uint4*)&sG[1][s][swzl][0] = v0;
    *(uint4*)&sG[2][s][swzl][0] = v1;
  }
  __syncthreads();

  // ---- phase 2: 640 granules/plane, lane-linear stores ----
  for (int g = tid; g < 640; g += 256) {
    const int s = g >> 6, l = g & 63;
    const int quad = l >> 4, m = l & 15;
    const int swzl = quad * 16 + ((m + quad + 4 * s) & 15);
    const size_t go = ((size_t)((R * KSTEPS + q * 10 + s) * 64) + l) * 8;
    *(uint4*)(Xbf + go) = *(const uint4*)&sG[0][s][swzl][0];
    *(uint4*)(A0  + go) = *(const uint4*)&sG[1][s][swzl][0];
    *(uint4*)(A1  + go) = *(const uint4*)&sG[2][s][swzl][0];
  }
}

// GEMM (unchanged from round 11): upper triangle of 32x32 tile grid, 528 blocks,
// 16x16 tiles; 4 waves split K into quarters; lane-linear fragment loads; LDS
// reduce; off-diagonal blocks also store the transposed tile.
__global__ __launch_bounds__(256, 2) void pcmd_gemm(
    const unsigned short* __restrict__ Xbf,
    const unsigned short* __restrict__ A0,
    const unsigned short* __restrict__ A1,
    const float* __restrict__ b,
    float* __restrict__ out)            // [510][510][2]
{
  __shared__ float sR[4][2][16][17];

  const int t = (int)blockIdx.x;        // 0..527
  int bi = (int)((65.0 - sqrt(4225.0 - 8.0 * (double)t)) * 0.5);
  {
    int s0 = bi * 32 - (bi * (bi - 1)) / 2;
    if (t < s0) { --bi; }
    int s1 = (bi + 1) * 32 - ((bi + 1) * bi) / 2;
    if (t >= s1) { ++bi; }
  }
  const int start = bi * 32 - (bi * (bi - 1)) / 2;
  const int bj = bi + (t - start);

  const int tid  = threadIdx.x;
  const int lane = tid & 63;
  const int wv   = tid >> 6;

  const unsigned short* pa0 = A0  + ((size_t)(bi * KSTEPS + wv * 10) * 64 + lane) * 8;
  const unsigned short* pa1 = A1  + ((size_t)(bi * KSTEPS + wv * 10) * 64 + lane) * 8;
  const unsigned short* pb  = Xbf + ((size_t)(bj * KSTEPS + wv * 10) * 64 + lane) * 8;

  bf16x8 ra0[4], ra1[4], rb[4];
  #pragma unroll
  for (int s = 0; s < 4; ++s) {
    ra0[s] = *(const bf16x8*)(pa0 + s * 512);
    ra1[s] = *(const bf16x8*)(pa1 + s * 512);
    rb[s]  = *(const bf16x8*)(pb  + s * 512);
  }

  f32x4 acc0 = {0.f, 0.f, 0.f, 0.f};
  f32x4 acc1 = {0.f, 0.f, 0.f, 0.f};

  #pragma unroll
  for (int s = 0; s < 10; ++s) {
    const int cur = s & 3;
    bf16x8 a0 = ra0[cur], a1 = ra1[cur], bb = rb[cur];
    if (s + 4 < 10) {
      ra0[cur] = *(const bf16x8*)(pa0 + (s + 4) * 512);
      ra1[cur] = *(const bf16x8*)(pa1 + (s + 4) * 512);
      rb[cur]  = *(const bf16x8*)(pb  + (s + 4) * 512);
    }
    acc0 = __builtin_amdgcn_mfma_f32_16x16x32_bf16(a0, bb, acc0, 0, 0, 0);
    acc1 = __builtin_amdgcn_mfma_f32_16x16x32_bf16(a1, bb, acc1, 0, 0, 0);
  }

  const int m = lane & 15, quad = lane >> 4;
  #pragma unroll
  for (int r = 0; r < 4; ++r) {
    sR[wv][0][quad * 4 + r][m] = acc0[r];
    sR[wv][1][quad * 4 + r][m] = acc1[r];
  }
  __syncthreads();

  const float b0 = b[0], b1 = b[1];
  const int il = tid >> 4, jl = tid & 15;

  {
    const int oi = bi * 16 + il, oj = bj * 16 + jl;
    if (oi < ODIM && oj < ODIM) {
      float2 v;
      v.x = sR[0][0][il][jl] + sR[1][0][il][jl] + sR[2][0][il][jl] + sR[3][0][il][jl] + b0;
      v.y = sR[0][1][il][jl] + sR[1][1][il][jl] + sR[2][1][il][jl] + sR[3][1][il][jl] + b1;
      *(float2*)(out + ((size_t)oi * ODIM + oj) * 2) = v;
    }
  }
  if (bi != bj) {
    const int oi = bj * 16 + il, oj = bi * 16 + jl;
    if (oi < ODIM && oj < ODIM) {
      float2 v;
      v.x = sR[0][0][jl][il] + sR[1][0][jl][il] + sR[2][0][jl][il] + sR[3][0][jl][il] + b0;
      v.y = sR[0][1][jl][il] + sR[1][1][jl][il] + sR[2][1][jl][il] + sR[3][1][jl][il] + b1;
      *(float2*)(out + ((size_t)oi * ODIM + oj) * 2) = v;
    }
  }
}

extern "C" void kernel_launch(void* const* d_in, const int* in_sizes, int n_in,
                              void* d_out, int out_size, void* d_ws, size_t ws_size,
                              hipStream_t stream) {
  const float* X = (const float*)d_in[0];
  const float* W = (const float*)d_in[1];
  const float* b = (const float*)d_in[2];
  float* out = (float*)d_out;
  (void)in_sizes; (void)n_in; (void)out_size; (void)ws_size;

  const size_t PLANE = (size_t)512 * D_DIM;        // elements per bf16 plane
  unsigned short* Xbf = (unsigned short*)d_ws;
  unsigned short* A0  = Xbf + PLANE;
  unsigned short* A1  = A0 + PLANE;

  hipLaunchKernelGGL(pcmd_prep, dim3(128), dim3(256), 0, stream, X, W, Xbf, A0, A1);
  hipLaunchKernelGGL(pcmd_gemm, dim3(528), dim3(256), 0, stream, Xbf, A0, A1, b, out);
}